// Round 1
// baseline (23976.987 us; speedup 1.0000x reference)
//
#include <hip/hip_runtime.h>
#include <cmath>

// Problem constants
#define NB 256      // grid blocks (== #CUs; LDS forces 1 block/CU -> co-resident)
#define NT 512      // threads per block (8 waves)
#define B_ 256
#define T_ 256
#define I_ 64
#define H_ 512
#define G4H 2048
#define BT 32       // batch rows per wg   (8 batch tiles)
#define UT 16       // hidden units per wg (32 unit tiles)
#define NCOL 64     // z-columns per wg = UT * 4 gates
#define R_ON_F 0.05f
#define ALPHA_F 1.0e-3f
#define LN_EPS_F 1.0e-5f

// Double-buffered hidden state (static __device__: independent of ws_size).
// Never read before written within a launch (t==0 uses zeros from LDS fill).
__device__ __align__(16) float g_h[2][B_ * H_];
__device__ unsigned g_cnt = 0;
__device__ unsigned g_gen = 0;

// Grid-wide barrier: generation-counting, agent-scope atomics.
// Safe because all 256 blocks are co-resident (96.6KB LDS -> 1 block/CU).
__device__ __forceinline__ void grid_barrier() {
    __threadfence();              // release: drain this thread's global writes
    __syncthreads();
    if (threadIdx.x == 0) {
        unsigned gen = __hip_atomic_load(&g_gen, __ATOMIC_RELAXED, __HIP_MEMORY_SCOPE_AGENT);
        unsigned arrived = __hip_atomic_fetch_add(&g_cnt, 1u, __ATOMIC_ACQ_REL, __HIP_MEMORY_SCOPE_AGENT);
        if (arrived == NB - 1u) {
            __hip_atomic_store(&g_cnt, 0u, __ATOMIC_RELAXED, __HIP_MEMORY_SCOPE_AGENT);
            __hip_atomic_store(&g_gen, gen + 1u, __ATOMIC_RELEASE, __HIP_MEMORY_SCOPE_AGENT);
        } else {
            while (__hip_atomic_load(&g_gen, __ATOMIC_RELAXED, __HIP_MEMORY_SCOPE_AGENT) == gen) {
                __builtin_amdgcn_s_sleep(2);
            }
        }
        __threadfence();          // acquire: invalidate L1/L2 before readers proceed
    }
    __syncthreads();
}

__global__ __launch_bounds__(NT) void plstm_scan_kernel(
    const float* __restrict__ x, const float* __restrict__ W,
    const float* __restrict__ U, const float* __restrict__ bias,
    const float* __restrict__ tau, const float* __restrict__ sph,
    const float* __restrict__ ln_g, const float* __restrict__ ln_b,
    const float* __restrict__ W1, const float* __restrict__ b1,
    const float* __restrict__ W2, const float* __restrict__ b2,
    float* __restrict__ out)
{
    __shared__ __align__(16) float hs[BT][H_];    // 64 KB: staged h tile (full rows)
    __shared__ __align__(16) float xs[BT][I_];    // 8 KB : x_t tile
    __shared__ __align__(16) float Ws[I_][NCOL];  // 16 KB: W column slice (resident)
    __shared__ __align__(16) float zs[BT][NCOL];  // 8 KB : z results
    __shared__ float bsz[NCOL];
    __shared__ float red[16];

    const int tid = threadIdx.x;
    const int bt = blockIdx.x >> 5;   // 0..7   batch tile
    const int ut = blockIdx.x & 31;   // 0..31  unit tile
    const int b0 = bt * BT;
    const int u0 = ut * UT;

    // Preload W slice + bias slice. Local col c -> global z-col j = (c>>4)*512 + u0 + (c&15)
    for (int idx = tid; idx < I_ * NCOL; idx += NT) {
        int k = idx >> 6, c = idx & 63;
        int j = ((c >> 4) << 9) + u0 + (c & 15);
        Ws[k][c] = W[k * G4H + j];
    }
    if (tid < NCOL) {
        int j = ((tid >> 4) << 9) + u0 + (tid & 15);
        bsz[tid] = bias[j];
    }

    // Compute-phase layout: 2 rows x 2 cols per thread
    const int tx2 = tid & 31;         // col pair {2*tx2, 2*tx2+1}
    const int ty  = tid >> 5;         // 0..15 -> rows {2*ty, 2*ty+1}
    const int c0 = tx2 * 2;
    const int r0 = ty * 2;
    const int j0 = ((c0 >> 4) << 9) + u0 + (c0 & 15);  // c0 even -> j0,j0+1 contiguous
    const float* Up = U + j0;

    // Update-phase layout: 1 (row,unit) pair per thread
    const int urow = tid >> 4;        // 0..31
    const int uuu  = tid & 15;        // 0..15
    const float tau_r = tau[u0 + uuu];
    const float s_r   = sph[u0 + uuu];
    float c_st = 0.f;                 // cell state lives in a register for all T

    int cur = 0;
    for (int t = 0; t < T_; ++t) {
        // ---- stage x_t tile (coalesced float4) ----
        {
            int xr = tid >> 4, xi4 = (tid & 15) << 2;
            *(float4*)&xs[xr][xi4] =
                *(const float4*)(x + (size_t)(b0 + xr) * (T_ * I_) + (size_t)t * I_ + xi4);
        }
        // ---- stage h tile ----
        {
            float4* hs4 = (float4*)&hs[0][0];
            if (t == 0) {
                const float4 z4 = make_float4(0.f, 0.f, 0.f, 0.f);
                #pragma unroll
                for (int it = 0; it < (BT * H_ / 4) / NT; ++it) hs4[tid + it * NT] = z4;
            } else {
                const float4* hsrc4 = (const float4*)(g_h[cur] + (size_t)b0 * H_);
                #pragma unroll
                for (int it = 0; it < (BT * H_ / 4) / NT; ++it)
                    hs4[tid + it * NT] = hsrc4[tid + it * NT];
            }
        }
        __syncthreads();

        // ---- z = x_t@W + h@U + b for (2 rows x 2 cols) ----
        const float2 bz = *(const float2*)&bsz[c0];
        float acc00 = bz.x, acc01 = bz.y, acc10 = bz.x, acc11 = bz.y;

        const float* xr0 = &xs[r0][0];
        const float* xr1 = &xs[r0 + 1][0];
        #pragma unroll 8
        for (int i = 0; i < I_; ++i) {
            float2 wv = *(const float2*)&Ws[i][c0];
            float x0 = xr0[i], x1 = xr1[i];
            acc00 = fmaf(x0, wv.x, acc00);
            acc01 = fmaf(x0, wv.y, acc01);
            acc10 = fmaf(x1, wv.x, acc10);
            acc11 = fmaf(x1, wv.y, acc11);
        }

        const float* hr0 = &hs[r0][0];
        const float* hr1 = &hs[r0 + 1][0];
        #pragma unroll 2
        for (int k4 = 0; k4 < H_ / 4; ++k4) {
            const int k = k4 << 2;
            const float4 ha = *(const float4*)(hr0 + k);   // ds_read_b128 (broadcast)
            const float4 hb = *(const float4*)(hr1 + k);
            const float2 u0v = *(const float2*)(Up + (size_t)(k + 0) * G4H);
            const float2 u1v = *(const float2*)(Up + (size_t)(k + 1) * G4H);
            const float2 u2v = *(const float2*)(Up + (size_t)(k + 2) * G4H);
            const float2 u3v = *(const float2*)(Up + (size_t)(k + 3) * G4H);
            acc00 = fmaf(ha.x, u0v.x, acc00); acc01 = fmaf(ha.x, u0v.y, acc01);
            acc10 = fmaf(hb.x, u0v.x, acc10); acc11 = fmaf(hb.x, u0v.y, acc11);
            acc00 = fmaf(ha.y, u1v.x, acc00); acc01 = fmaf(ha.y, u1v.y, acc01);
            acc10 = fmaf(hb.y, u1v.x, acc10); acc11 = fmaf(hb.y, u1v.y, acc11);
            acc00 = fmaf(ha.z, u2v.x, acc00); acc01 = fmaf(ha.z, u2v.y, acc01);
            acc10 = fmaf(hb.z, u2v.x, acc10); acc11 = fmaf(hb.z, u2v.y, acc11);
            acc00 = fmaf(ha.w, u3v.x, acc00); acc01 = fmaf(ha.w, u3v.y, acc01);
            acc10 = fmaf(hb.w, u3v.x, acc10); acc11 = fmaf(hb.w, u3v.y, acc11);
        }

        *(float2*)&zs[r0][c0]     = make_float2(acc00, acc01);
        *(float2*)&zs[r0 + 1][c0] = make_float2(acc10, acc11);
        __syncthreads();

        // ---- gate + phased time-gate update for owned (row, unit) ----
        {
            const float zi = zs[urow][uuu];
            const float zf = zs[urow][16 + uuu];
            const float zg = zs[urow][32 + uuu];
            const float zo = zs[urow][48 + uuu];
            const float si = 1.f / (1.f + __expf(-zi));
            const float sf = 1.f / (1.f + __expf(-zf));
            const float so = 1.f / (1.f + __expf(-zo));
            const float ct = sf * c_st + si * tanhf(zg);
            const float ht = so * tanhf(ct);
            // k(t): python-mod semantics (result sign = divisor sign)
            float a = (float)t - s_r;
            float r = fmodf(a, tau_r);
            if (r < 0.f) r += tau_r;
            const float phi = r / tau_r;
            float kk;
            if (phi < 0.5f * R_ON_F)      kk = phi * (2.f / R_ON_F);
            else if (phi < R_ON_F)        kk = 2.f - phi * (2.f / R_ON_F);
            else                          kk = ALPHA_F * phi;
            const float hprev = hs[urow][u0 + uuu];
            const float hn = kk * ht + (1.f - kk) * hprev;
            c_st = kk * ct + (1.f - kk) * c_st;
            g_h[cur ^ 1][(size_t)(b0 + urow) * H_ + (u0 + uuu)] = hn;
        }
        cur ^= 1;
        grid_barrier();
    }

    // ---- epilogue: wg b handles batch row b. LN + collapsed dense head ----
    {
        const int b = blockIdx.x;
        const float* hrow = g_h[cur] + (size_t)b * H_;
        const float hv = hrow[tid];               // u = tid (512 threads = H)
        float s1 = hv, s2 = hv * hv;
        #pragma unroll
        for (int off = 32; off > 0; off >>= 1) {
            s1 += __shfl_down(s1, off, 64);
            s2 += __shfl_down(s2, off, 64);
        }
        const int wv = tid >> 6, ln = tid & 63;
        if (ln == 0) { red[wv] = s1; red[8 + wv] = s2; }
        __syncthreads();
        float S1 = 0.f, S2 = 0.f;
        #pragma unroll
        for (int w = 0; w < 8; ++w) { S1 += red[w]; S2 += red[8 + w]; }
        const float mu = S1 * (1.f / 512.f);
        const float var = S2 * (1.f / 512.f) - mu * mu;
        const float rstd = rsqrtf(var + LN_EPS_F);
        const float hn = (hv - mu) * rstd * ln_g[tid] + ln_b[tid];
        // w12[u] = sum_d W1[u,d] * W2[d]
        float w12 = 0.f;
        const float* w1p = W1 + (size_t)tid * 256;
        #pragma unroll 4
        for (int d = 0; d < 256; ++d) w12 = fmaf(w1p[d], W2[d], w12);
        float contrib = hn * w12;
        if (tid < 256) contrib = fmaf(b1[tid], W2[tid], contrib);  // bias-through-W2 term
        #pragma unroll
        for (int off = 32; off > 0; off >>= 1) contrib += __shfl_down(contrib, off, 64);
        __syncthreads();
        if (ln == 0) red[wv] = contrib;
        __syncthreads();
        if (tid == 0) {
            float tot = b2[0];
            #pragma unroll
            for (int w = 0; w < 8; ++w) tot += red[w];
            out[b] = tot;
        }
    }
}

extern "C" void kernel_launch(void* const* d_in, const int* in_sizes, int n_in,
                              void* d_out, int out_size, void* d_ws, size_t ws_size,
                              hipStream_t stream) {
    const float* x   = (const float*)d_in[0];
    const float* W   = (const float*)d_in[1];
    const float* U   = (const float*)d_in[2];
    const float* b   = (const float*)d_in[3];
    const float* tau = (const float*)d_in[4];
    const float* s   = (const float*)d_in[5];
    const float* lng = (const float*)d_in[6];
    const float* lnb = (const float*)d_in[7];
    const float* W1  = (const float*)d_in[8];
    const float* b1  = (const float*)d_in[9];
    const float* W2  = (const float*)d_in[10];
    const float* b2  = (const float*)d_in[11];
    float* out = (float*)d_out;
    plstm_scan_kernel<<<dim3(NB), dim3(NT), 0, stream>>>(
        x, W, U, b, tau, s, lng, lnb, W1, b1, W2, b2, out);
}

// Round 2
// 6241.993 us; speedup vs baseline: 3.8412x; 3.8412x over previous
//
#include <hip/hip_runtime.h>
#include <cmath>

#define NB 256
#define NT 512
#define B_ 256
#define T_ 256
#define I_ 64
#define H_ 512
#define G4H 2048
#define K_ 576      // I + H combined GEMM depth
#define BT 32       // batch rows per wg
#define UT 16       // hidden units per wg -> 64 z-cols
#define NCOL 64
#define KCH 36      // K_ / 16 ty-groups
#define R_ON_F 0.05f
#define ALPHA_F 1.0e-3f
#define LN_EPS_F 1.0e-5f

// Double-buffered hidden state. Written fully every step before being read.
__device__ __align__(16) float g_h[2][B_ * H_];

// Hierarchical barrier state: every counter on its own 256B line.
struct alignas(256) PadCnt { unsigned v; unsigned pad[63]; };
__device__ PadCnt g_grp[8];
__device__ PadCnt g_root;
__device__ PadCnt g_gen;

// Grid barrier: 32 arrivals per group -> 8 groups -> root -> gen flip.
// Release on arrival RMW (wbl2 flushes only dirty h lines; weights live in
// VGPRs so the L2 inv on acquire costs only the h/x refetch we need anyway).
__device__ __forceinline__ void grid_barrier(int grp) {
    __syncthreads();
    if (threadIdx.x == 0) {
        unsigned gen = __hip_atomic_load(&g_gen.v, __ATOMIC_RELAXED, __HIP_MEMORY_SCOPE_AGENT);
        unsigned a = __hip_atomic_fetch_add(&g_grp[grp].v, 1u, __ATOMIC_ACQ_REL, __HIP_MEMORY_SCOPE_AGENT);
        if (a == 31u) {
            __hip_atomic_store(&g_grp[grp].v, 0u, __ATOMIC_RELAXED, __HIP_MEMORY_SCOPE_AGENT);
            unsigned ra = __hip_atomic_fetch_add(&g_root.v, 1u, __ATOMIC_ACQ_REL, __HIP_MEMORY_SCOPE_AGENT);
            if (ra == 7u) {
                __hip_atomic_store(&g_root.v, 0u, __ATOMIC_RELAXED, __HIP_MEMORY_SCOPE_AGENT);
                __hip_atomic_store(&g_gen.v, gen + 1u, __ATOMIC_RELEASE, __HIP_MEMORY_SCOPE_AGENT);
            } else {
                while (__hip_atomic_load(&g_gen.v, __ATOMIC_RELAXED, __HIP_MEMORY_SCOPE_AGENT) == gen)
                    __builtin_amdgcn_s_sleep(4);
            }
        } else {
            while (__hip_atomic_load(&g_gen.v, __ATOMIC_RELAXED, __HIP_MEMORY_SCOPE_AGENT) == gen)
                __builtin_amdgcn_s_sleep(4);
        }
        // acquire: L1/L2 invalidate so cross-XCD h stores are visible
        (void)__hip_atomic_load(&g_gen.v, __ATOMIC_ACQUIRE, __HIP_MEMORY_SCOPE_AGENT);
    }
    __syncthreads();
}

__global__ __launch_bounds__(NT) void plstm_scan_kernel(
    const float* __restrict__ x, const float* __restrict__ W,
    const float* __restrict__ U, const float* __restrict__ bias,
    const float* __restrict__ tau, const float* __restrict__ sph,
    const float* __restrict__ ln_g, const float* __restrict__ ln_b,
    const float* __restrict__ W1, const float* __restrict__ b1,
    const float* __restrict__ W2, const float* __restrict__ b2,
    float* __restrict__ out)
{
    __shared__ __align__(16) float es[BT][K_];        // 72 KB: [x_t | h] operand tile
    __shared__ __align__(16) float pb[8][BT][NCOL];   // 64 KB: per-wave partials
    __shared__ __align__(16) float zs[BT][NCOL];      // 8 KB : reduced z
    __shared__ __align__(16) float bsz[NCOL];
    __shared__ float red[16];

    const int tid = threadIdx.x;
    const int grp = blockIdx.x & 7;
    const int bt = blockIdx.x >> 5;   // 0..7  batch tile
    const int ut = blockIdx.x & 31;   // 0..31 unit tile
    const int b0 = bt * BT;
    const int u0 = ut * UT;

    // --- split-K thread layout: 2 cols x 36-k chunk, weights in VGPRs ---
    const int tx2 = tid & 31;         // col pair c0 = 2*tx2
    const int ty  = tid >> 5;         // k-chunk 0..15
    const int c0 = tx2 * 2;
    const int ks = ty * KCH;
    const int j0 = ((c0 >> 4) << 9) + u0 + (c0 & 15);   // global z-col (c0 even -> j0,j0+1 contig)

    float2 wr[KCH];
    #pragma unroll
    for (int i = 0; i < KCH; ++i) {
        const int k = ks + i;
        const float* src = (k < I_) ? (W + (size_t)k * G4H + j0)
                                    : (U + (size_t)(k - I_) * G4H + j0);
        wr[i] = *(const float2*)src;
    }
    if (tid < NCOL) {
        int j = ((tid >> 4) << 9) + u0 + (tid & 15);
        bsz[tid] = bias[j];
    }

    // --- gate-update layout: one (row, unit) per thread ---
    const int urow = tid >> 4;
    const int uuu  = tid & 15;
    const float tau_r = tau[u0 + uuu];
    const float s_r   = sph[u0 + uuu];
    float c_st = 0.f;

    const int wv = tid >> 6;          // wave id 0..7
    const int lane = tid & 63;

    int cur = 0;
    for (int t = 0; t < T_; ++t) {
        // ---- stage x_t into es[:][0:64] ----
        {
            int xr = tid >> 4, xi4 = (tid & 15) << 2;
            *(float4*)&es[xr][xi4] =
                *(const float4*)(x + ((size_t)(b0 + xr) * T_ + t) * I_ + xi4);
        }
        // ---- stage h into es[:][64:576] ----
        if (t == 0) {
            const float4 z4 = make_float4(0.f, 0.f, 0.f, 0.f);
            #pragma unroll
            for (int it = 0; it < 8; ++it) {
                int idx = tid + it * NT;            // 0..4095 float4 slots
                int r = idx >> 7, k4 = (idx & 127) << 2;
                *(float4*)&es[r][I_ + k4] = z4;
            }
        } else {
            const float* hbase = g_h[cur] + (size_t)b0 * H_;
            #pragma unroll
            for (int it = 0; it < 8; ++it) {
                int idx = tid + it * NT;
                int r = idx >> 7, k4 = (idx & 127) << 2;
                *(float4*)&es[r][I_ + k4] = *(const float4*)(hbase + (size_t)r * H_ + k4);
            }
        }
        __syncthreads();

        // ---- partial GEMM: acc[r][c0..c0+1] over this thread's 36 k's ----
        float2 acc[BT];
        #pragma unroll
        for (int r = 0; r < BT; ++r) acc[r] = make_float2(0.f, 0.f);
        #pragma unroll
        for (int r = 0; r < BT; ++r) {
            const float* er = &es[r][ks];
            float2 a = acc[r];
            #pragma unroll
            for (int i = 0; i < 9; ++i) {
                const float4 h4 = *(const float4*)(er + 4 * i);
                a.x = fmaf(h4.x, wr[4*i+0].x, a.x); a.y = fmaf(h4.x, wr[4*i+0].y, a.y);
                a.x = fmaf(h4.y, wr[4*i+1].x, a.x); a.y = fmaf(h4.y, wr[4*i+1].y, a.y);
                a.x = fmaf(h4.z, wr[4*i+2].x, a.x); a.y = fmaf(h4.z, wr[4*i+2].y, a.y);
                a.x = fmaf(h4.w, wr[4*i+3].x, a.x); a.y = fmaf(h4.w, wr[4*i+3].y, a.y);
            }
            acc[r] = a;
        }

        // ---- fold the two k-chunks within each wave (lane L += lane L+32) ----
        #pragma unroll
        for (int r = 0; r < BT; ++r) {
            acc[r].x += __shfl_down(acc[r].x, 32);
            acc[r].y += __shfl_down(acc[r].y, 32);
        }
        if (lane < 32) {
            #pragma unroll
            for (int r = 0; r < BT; ++r)
                *(float2*)&pb[wv][r][2 * lane] = acc[r];
        }
        __syncthreads();

        // ---- reduce 8 wave-partials + bias -> zs ----
        {
            const int r = tid >> 4, c4 = (tid & 15) << 2;
            float4 s = *(const float4*)&bsz[c4];
            #pragma unroll
            for (int w = 0; w < 8; ++w) {
                const float4 p = *(const float4*)&pb[w][r][c4];
                s.x += p.x; s.y += p.y; s.z += p.z; s.w += p.w;
            }
            *(float4*)&zs[r][c4] = s;
        }
        __syncthreads();

        // ---- gates + phased time-gate ----
        {
            const float zi = zs[urow][uuu];
            const float zf = zs[urow][16 + uuu];
            const float zg = zs[urow][32 + uuu];
            const float zo = zs[urow][48 + uuu];
            const float si = 1.f / (1.f + __expf(-zi));
            const float sf = 1.f / (1.f + __expf(-zf));
            const float so = 1.f / (1.f + __expf(-zo));
            const float ct = sf * c_st + si * tanhf(zg);
            const float ht = so * tanhf(ct);
            float aa = (float)t - s_r;
            float rr = fmodf(aa, tau_r);
            if (rr < 0.f) rr += tau_r;
            const float phi = rr / tau_r;
            float kk;
            if (phi < 0.5f * R_ON_F)      kk = phi * (2.f / R_ON_F);
            else if (phi < R_ON_F)        kk = 2.f - phi * (2.f / R_ON_F);
            else                          kk = ALPHA_F * phi;
            const float hprev = es[urow][I_ + u0 + uuu];
            const float hn = kk * ht + (1.f - kk) * hprev;
            c_st = kk * ct + (1.f - kk) * c_st;
            g_h[cur ^ 1][(size_t)(b0 + urow) * H_ + (u0 + uuu)] = hn;
        }
        cur ^= 1;
        grid_barrier(grp);
    }

    // ---- epilogue: wg b handles batch row b. LN + collapsed dense head ----
    {
        const int b = blockIdx.x;
        const float* hrow = g_h[cur] + (size_t)b * H_;
        const float hv = hrow[tid];
        float s1 = hv, s2 = hv * hv;
        #pragma unroll
        for (int off = 32; off > 0; off >>= 1) {
            s1 += __shfl_down(s1, off, 64);
            s2 += __shfl_down(s2, off, 64);
        }
        const int ln = tid & 63;
        if (ln == 0) { red[wv] = s1; red[8 + wv] = s2; }
        __syncthreads();
        float S1 = 0.f, S2 = 0.f;
        #pragma unroll
        for (int w = 0; w < 8; ++w) { S1 += red[w]; S2 += red[8 + w]; }
        const float mu = S1 * (1.f / 512.f);
        const float var = S2 * (1.f / 512.f) - mu * mu;
        const float rstd = rsqrtf(var + LN_EPS_F);
        const float hn = (hv - mu) * rstd * ln_g[tid] + ln_b[tid];
        float w12 = 0.f;
        const float* w1p = W1 + (size_t)tid * 256;
        #pragma unroll 4
        for (int d = 0; d < 256; ++d) w12 = fmaf(w1p[d], W2[d], w12);
        float contrib = hn * w12;
        if (tid < 256) contrib = fmaf(b1[tid], W2[tid], contrib);
        #pragma unroll
        for (int off = 32; off > 0; off >>= 1) contrib += __shfl_down(contrib, off, 64);
        __syncthreads();
        if (ln == 0) red[wv] = contrib;
        __syncthreads();
        if (tid == 0) {
            float tot = b2[0];
            #pragma unroll
            for (int w = 0; w < 8; ++w) tot += red[w];
            out[b] = tot;
        }
    }
}

extern "C" void kernel_launch(void* const* d_in, const int* in_sizes, int n_in,
                              void* d_out, int out_size, void* d_ws, size_t ws_size,
                              hipStream_t stream) {
    const float* x   = (const float*)d_in[0];
    const float* W   = (const float*)d_in[1];
    const float* U   = (const float*)d_in[2];
    const float* b   = (const float*)d_in[3];
    const float* tau = (const float*)d_in[4];
    const float* s   = (const float*)d_in[5];
    const float* lng = (const float*)d_in[6];
    const float* lnb = (const float*)d_in[7];
    const float* W1  = (const float*)d_in[8];
    const float* b1  = (const float*)d_in[9];
    const float* W2  = (const float*)d_in[10];
    const float* b2  = (const float*)d_in[11];
    float* out = (float*)d_out;
    plstm_scan_kernel<<<dim3(NB), dim3(NT), 0, stream>>>(
        x, W, U, b, tau, s, lng, lnb, W1, b1, W2, b2, out);
}

// Round 3
// 3310.867 us; speedup vs baseline: 7.2419x; 1.8853x over previous
//
#include <hip/hip_runtime.h>
#include <cmath>

#define NB 256
#define NT 512
#define B_ 256
#define T_ 256
#define I_ 64
#define H_ 512
#define G4H 2048
#define K_ 576
#define BT 32
#define UT 16
#define NCOL 64
#define KCH 36
#define R_ON_F 0.05f
#define ALPHA_F 1.0e-3f
#define LN_EPS_F 1.0e-5f

typedef float v4f __attribute__((ext_vector_type(4)));

// Hidden-state double buffer. ALL accesses bypass L1/L2 (sc0 sc1) so the
// grid barrier needs no cache maintenance and L2 stays warm for x/W/U.
__device__ __align__(16) float g_h[2][B_ * H_];

struct alignas(256) PadCnt { unsigned v; unsigned pad[63]; };
__device__ PadCnt g_grp[8];
__device__ PadCnt g_root;
__device__ PadCnt g_gen;

// Grid barrier: all RELAXED system-scope atomics (sc0 sc1 at the coherence
// point, NO buffer_wbl2/buffer_inv). h visibility is guaranteed by the
// explicit s_waitcnt vmcnt(0) each thread executes after its bypass store,
// before __syncthreads -> before thread0 arrives.
__device__ __forceinline__ void grid_barrier(int grp) {
    __syncthreads();
    if (threadIdx.x == 0) {
        unsigned gen = __hip_atomic_load(&g_gen.v, __ATOMIC_RELAXED, __HIP_MEMORY_SCOPE_SYSTEM);
        unsigned a = __hip_atomic_fetch_add(&g_grp[grp].v, 1u, __ATOMIC_RELAXED, __HIP_MEMORY_SCOPE_SYSTEM);
        if (a == 31u) {
            __hip_atomic_store(&g_grp[grp].v, 0u, __ATOMIC_RELAXED, __HIP_MEMORY_SCOPE_SYSTEM);
            unsigned ra = __hip_atomic_fetch_add(&g_root.v, 1u, __ATOMIC_RELAXED, __HIP_MEMORY_SCOPE_SYSTEM);
            if (ra == 7u) {
                __hip_atomic_store(&g_root.v, 0u, __ATOMIC_RELAXED, __HIP_MEMORY_SCOPE_SYSTEM);
                __hip_atomic_store(&g_gen.v, gen + 1u, __ATOMIC_RELAXED, __HIP_MEMORY_SCOPE_SYSTEM);
            } else {
                while (__hip_atomic_load(&g_gen.v, __ATOMIC_RELAXED, __HIP_MEMORY_SCOPE_SYSTEM) == gen)
                    __builtin_amdgcn_s_sleep(1);
            }
        } else {
            while (__hip_atomic_load(&g_gen.v, __ATOMIC_RELAXED, __HIP_MEMORY_SCOPE_SYSTEM) == gen)
                __builtin_amdgcn_s_sleep(1);
        }
    }
    __syncthreads();
}

__global__ __launch_bounds__(NT, 2) void plstm_scan_kernel(
    const float* __restrict__ x, const float* __restrict__ W,
    const float* __restrict__ U, const float* __restrict__ bias,
    const float* __restrict__ tau, const float* __restrict__ sph,
    const float* __restrict__ ln_g, const float* __restrict__ ln_b,
    const float* __restrict__ W1, const float* __restrict__ b1,
    const float* __restrict__ W2, const float* __restrict__ b2,
    float* __restrict__ out)
{
    __shared__ __align__(16) float es[BT][K_];        // 72 KB [x_t | h]
    __shared__ __align__(16) float pb[8][BT][NCOL];   // 64 KB wave partials
    __shared__ __align__(16) float zs[BT][NCOL];      // 8 KB
    __shared__ __align__(16) float bsz[NCOL];
    __shared__ float red[16];

    const int tid = threadIdx.x;
    const int grp = blockIdx.x & 7;
    const int bt = blockIdx.x >> 5;
    const int ut = blockIdx.x & 31;
    const int b0 = bt * BT;
    const int u0 = ut * UT;

    const int tx2 = tid & 31;
    const int ty  = tid >> 5;
    const int c0 = tx2 * 2;
    const int ks = ty * KCH;
    const int j0 = ((c0 >> 4) << 9) + u0 + (c0 & 15);

    float2 wr[KCH];
    #pragma unroll
    for (int i = 0; i < KCH; ++i) {
        const int k = ks + i;
        const float* src = (k < I_) ? (W + (size_t)k * G4H + j0)
                                    : (U + (size_t)(k - I_) * G4H + j0);
        wr[i] = *(const float2*)src;
    }
    if (tid < NCOL) {
        int j = ((tid >> 4) << 9) + u0 + (tid & 15);
        bsz[tid] = bias[j];
    }

    const int urow = tid >> 4;
    const int uuu  = tid & 15;
    const float tau_r = tau[u0 + uuu];
    const float s_r   = sph[u0 + uuu];
    float c_st = 0.f;

    const int wv = tid >> 6;
    const int lane = tid & 63;

    // h-staging geometry: idx = tid + 512*it -> row r0+4*it, col k4 (same all it)
    const int hr0 = tid >> 7;
    const int hk4 = (tid & 127) << 2;

    int cur = 0;
    for (int t = 0; t < T_; ++t) {
        // ---- stage x_t (cached loads: L2 stays warm — no more invalidates) ----
        {
            int xr = tid >> 4, xi4 = (tid & 15) << 2;
            *(float4*)&es[xr][xi4] =
                *(const float4*)(x + ((size_t)(b0 + xr) * T_ + t) * I_ + xi4);
        }
        // ---- stage h via sc0sc1 bypass loads (fresh from coherence point) ----
        if (t == 0) {
            const v4f z4 = {0.f, 0.f, 0.f, 0.f};
            #pragma unroll
            for (int it = 0; it < 8; ++it)
                *(v4f*)&es[hr0 + 4 * it][I_ + hk4] = z4;
        } else {
            const float* hb = g_h[cur] + (size_t)(b0 + hr0) * H_ + hk4;
            v4f a0, a1, a2, a3, a4, a5, a6, a7;
            asm volatile(
                "global_load_dwordx4 %0, %8, off sc0 sc1\n\t"
                "global_load_dwordx4 %1, %9, off sc0 sc1\n\t"
                "global_load_dwordx4 %2, %10, off sc0 sc1\n\t"
                "global_load_dwordx4 %3, %11, off sc0 sc1\n\t"
                "global_load_dwordx4 %4, %12, off sc0 sc1\n\t"
                "global_load_dwordx4 %5, %13, off sc0 sc1\n\t"
                "global_load_dwordx4 %6, %14, off sc0 sc1\n\t"
                "global_load_dwordx4 %7, %15, off sc0 sc1\n\t"
                "s_waitcnt vmcnt(0)"
                : "=&v"(a0), "=&v"(a1), "=&v"(a2), "=&v"(a3),
                  "=&v"(a4), "=&v"(a5), "=&v"(a6), "=&v"(a7)
                : "v"(hb),            "v"(hb + 4 * H_),
                  "v"(hb + 8 * H_),   "v"(hb + 12 * H_),
                  "v"(hb + 16 * H_),  "v"(hb + 20 * H_),
                  "v"(hb + 24 * H_),  "v"(hb + 28 * H_)
                : "memory");
            *(v4f*)&es[hr0 +  0][I_ + hk4] = a0;
            *(v4f*)&es[hr0 +  4][I_ + hk4] = a1;
            *(v4f*)&es[hr0 +  8][I_ + hk4] = a2;
            *(v4f*)&es[hr0 + 12][I_ + hk4] = a3;
            *(v4f*)&es[hr0 + 16][I_ + hk4] = a4;
            *(v4f*)&es[hr0 + 20][I_ + hk4] = a5;
            *(v4f*)&es[hr0 + 24][I_ + hk4] = a6;
            *(v4f*)&es[hr0 + 28][I_ + hk4] = a7;
        }
        __syncthreads();

        // ---- split-K partial GEMM: 32 rows x 2 cols over 36 k's ----
        float2 acc[BT];
        #pragma unroll
        for (int r = 0; r < BT; ++r) acc[r] = make_float2(0.f, 0.f);
        #pragma unroll
        for (int r = 0; r < BT; ++r) {
            const float* er = &es[r][ks];
            float2 a = acc[r];
            #pragma unroll
            for (int i = 0; i < 9; ++i) {
                const float4 h4 = *(const float4*)(er + 4 * i);
                a.x = fmaf(h4.x, wr[4*i+0].x, a.x); a.y = fmaf(h4.x, wr[4*i+0].y, a.y);
                a.x = fmaf(h4.y, wr[4*i+1].x, a.x); a.y = fmaf(h4.y, wr[4*i+1].y, a.y);
                a.x = fmaf(h4.z, wr[4*i+2].x, a.x); a.y = fmaf(h4.z, wr[4*i+2].y, a.y);
                a.x = fmaf(h4.w, wr[4*i+3].x, a.x); a.y = fmaf(h4.w, wr[4*i+3].y, a.y);
            }
            acc[r] = a;
        }

        #pragma unroll
        for (int r = 0; r < BT; ++r) {
            acc[r].x += __shfl_down(acc[r].x, 32);
            acc[r].y += __shfl_down(acc[r].y, 32);
        }
        if (lane < 32) {
            #pragma unroll
            for (int r = 0; r < BT; ++r)
                *(float2*)&pb[wv][r][2 * lane] = acc[r];
        }
        __syncthreads();

        {
            const int r = tid >> 4, c4 = (tid & 15) << 2;
            float4 s = *(const float4*)&bsz[c4];
            #pragma unroll
            for (int w = 0; w < 8; ++w) {
                const float4 p = *(const float4*)&pb[w][r][c4];
                s.x += p.x; s.y += p.y; s.z += p.z; s.w += p.w;
            }
            *(float4*)&zs[r][c4] = s;
        }
        __syncthreads();

        // ---- gates + phased time-gate; h store bypasses caches ----
        {
            const float zi = zs[urow][uuu];
            const float zf = zs[urow][16 + uuu];
            const float zg = zs[urow][32 + uuu];
            const float zo = zs[urow][48 + uuu];
            const float si = 1.f / (1.f + __expf(-zi));
            const float sf = 1.f / (1.f + __expf(-zf));
            const float so = 1.f / (1.f + __expf(-zo));
            const float ct = sf * c_st + si * tanhf(zg);
            const float ht = so * tanhf(ct);
            float aa = (float)t - s_r;
            float rr = fmodf(aa, tau_r);
            if (rr < 0.f) rr += tau_r;
            const float phi = rr / tau_r;
            float kk;
            if (phi < 0.5f * R_ON_F)      kk = phi * (2.f / R_ON_F);
            else if (phi < R_ON_F)        kk = 2.f - phi * (2.f / R_ON_F);
            else                          kk = ALPHA_F * phi;
            const float hprev = es[urow][I_ + u0 + uuu];
            const float hn = kk * ht + (1.f - kk) * hprev;
            c_st = kk * ct + (1.f - kk) * c_st;
            float* gp = g_h[cur ^ 1] + (size_t)(b0 + urow) * H_ + (u0 + uuu);
            asm volatile("global_store_dword %0, %1, off sc0 sc1"
                         :: "v"(gp), "v"(hn) : "memory");
            asm volatile("s_waitcnt vmcnt(0)" ::: "memory");
        }
        cur ^= 1;
        grid_barrier(grp);
    }

    // ---- epilogue: LN + collapsed head (h via bypass: L2 may hold stale
    //      lines from a previous graph replay) ----
    {
        const int b = blockIdx.x;
        float hv;
        const float* hp = g_h[cur] + (size_t)b * H_ + tid;
        asm volatile("global_load_dword %0, %1, off sc0 sc1\n\ts_waitcnt vmcnt(0)"
                     : "=v"(hv) : "v"(hp) : "memory");
        float s1 = hv, s2 = hv * hv;
        #pragma unroll
        for (int off = 32; off > 0; off >>= 1) {
            s1 += __shfl_down(s1, off, 64);
            s2 += __shfl_down(s2, off, 64);
        }
        const int ln = tid & 63;
        if (ln == 0) { red[wv] = s1; red[8 + wv] = s2; }
        __syncthreads();
        float S1 = 0.f, S2 = 0.f;
        #pragma unroll
        for (int w = 0; w < 8; ++w) { S1 += red[w]; S2 += red[8 + w]; }
        const float mu = S1 * (1.f / 512.f);
        const float var = S2 * (1.f / 512.f) - mu * mu;
        const float rstd = rsqrtf(var + LN_EPS_F);
        const float hn = (hv - mu) * rstd * ln_g[tid] + ln_b[tid];
        float w12 = 0.f;
        const float* w1p = W1 + (size_t)tid * 256;
        #pragma unroll 4
        for (int d = 0; d < 256; ++d) w12 = fmaf(w1p[d], W2[d], w12);
        float contrib = hn * w12;
        if (tid < 256) contrib = fmaf(b1[tid], W2[tid], contrib);
        #pragma unroll
        for (int off = 32; off > 0; off >>= 1) contrib += __shfl_down(contrib, off, 64);
        __syncthreads();
        if (ln == 0) red[wv] = contrib;
        __syncthreads();
        if (tid == 0) {
            float tot = b2[0];
            #pragma unroll
            for (int w = 0; w < 8; ++w) tot += red[w];
            out[b] = tot;
        }
    }
}

extern "C" void kernel_launch(void* const* d_in, const int* in_sizes, int n_in,
                              void* d_out, int out_size, void* d_ws, size_t ws_size,
                              hipStream_t stream) {
    const float* x   = (const float*)d_in[0];
    const float* W   = (const float*)d_in[1];
    const float* U   = (const float*)d_in[2];
    const float* b   = (const float*)d_in[3];
    const float* tau = (const float*)d_in[4];
    const float* s   = (const float*)d_in[5];
    const float* lng = (const float*)d_in[6];
    const float* lnb = (const float*)d_in[7];
    const float* W1  = (const float*)d_in[8];
    const float* b1  = (const float*)d_in[9];
    const float* W2  = (const float*)d_in[10];
    const float* b2  = (const float*)d_in[11];
    float* out = (float*)d_out;
    plstm_scan_kernel<<<dim3(NB), dim3(NT), 0, stream>>>(
        x, W, U, b, tau, s, lng, lnb, W1, b1, W2, b2, out);
}

// Round 6
// 1371.693 us; speedup vs baseline: 17.4798x; 2.4137x over previous
//
#include <hip/hip_runtime.h>
#include <cmath>

#define NB 256
#define NT 512
#define B_ 256
#define T_ 256
#define I_ 64
#define H_ 512
#define G4H 2048
#define BT 32
#define UT 16
#define PK 584            // padded A row length (elems): 584*2B=1168B, 16B-aligned rows
#define ZP 68             // padded zs row
#define R_ON_F 0.05f
#define ALPHA_F 1.0e-3f
#define LN_EPS_F 1.0e-5f

typedef _Float16 h8 __attribute__((ext_vector_type(8)));
typedef _Float16 h4v __attribute__((ext_vector_type(4)));
typedef float f4 __attribute__((ext_vector_type(4)));
typedef float v4f __attribute__((ext_vector_type(4)));

// Hidden-state double buffer; all accesses bypass caches (sc0 sc1).
__device__ __align__(16) float g_h[2][B_ * H_];

// Per-bt-group barrier state (32 blocks per group), one line per counter.
struct alignas(256) PadCnt { unsigned v; unsigned pad[63]; };
__device__ PadCnt g_cnt2[8];
__device__ PadCnt g_gen2[8];

// 32-arrival group barrier (only blocks sharing batch rows need to sync).
// Relaxed system-scope atomics; h-store visibility via each thread's explicit
// vmcnt(0) drain before __syncthreads -> before thread0 arrives here.
__device__ __forceinline__ void group_barrier(int g) {
    __syncthreads();
    if (threadIdx.x == 0) {
        unsigned gen = __hip_atomic_load(&g_gen2[g].v, __ATOMIC_RELAXED, __HIP_MEMORY_SCOPE_SYSTEM);
        unsigned a = __hip_atomic_fetch_add(&g_cnt2[g].v, 1u, __ATOMIC_RELAXED, __HIP_MEMORY_SCOPE_SYSTEM);
        if (a == 31u) {
            __hip_atomic_store(&g_cnt2[g].v, 0u, __ATOMIC_RELAXED, __HIP_MEMORY_SCOPE_SYSTEM);
            asm volatile("s_waitcnt vmcnt(0)" ::: "memory");
            __hip_atomic_store(&g_gen2[g].v, gen + 1u, __ATOMIC_RELAXED, __HIP_MEMORY_SCOPE_SYSTEM);
        } else {
            while (__hip_atomic_load(&g_gen2[g].v, __ATOMIC_RELAXED, __HIP_MEMORY_SCOPE_SYSTEM) == gen)
                __builtin_amdgcn_s_sleep(1);
        }
    }
    __syncthreads();
}

struct HiLo { _Float16 hi, lo; };
__device__ __forceinline__ HiLo cvt_hilo(float v) {
    HiLo r;
    r.hi = (_Float16)v;
    r.lo = (_Float16)(v - (float)r.hi);
    return r;
}

__global__ __launch_bounds__(NT, 1) void plstm_scan_kernel(
    const float* __restrict__ x, const float* __restrict__ W,
    const float* __restrict__ U, const float* __restrict__ bias,
    const float* __restrict__ tau, const float* __restrict__ sph,
    const float* __restrict__ ln_g, const float* __restrict__ ln_b,
    const float* __restrict__ W1, const float* __restrict__ b1,
    const float* __restrict__ W2, const float* __restrict__ b2,
    float* __restrict__ out)
{
    __shared__ __align__(16) _Float16 Ah[BT][PK];   // 36.5 KB hi operand [x|h]
    __shared__ __align__(16) _Float16 Al[BT][PK];   // 36.5 KB lo operand
    __shared__ __align__(16) float zs[BT][ZP];      // 8.5 KB z tile
    __shared__ __align__(16) float bsz[64];
    __shared__ float red[16];

    const int tid = threadIdx.x;
    const int bt = blockIdx.x >> 5;    // group: blocks sharing batch rows
    const int ut = blockIdx.x & 31;
    const int b0 = bt * BT;
    const int u0 = ut * UT;

    const int wv = tid >> 6;           // wave 0..7
    const int lane = tid & 63;
    const int mt = wv & 1;             // M tile (16 rows)
    const int nt = wv >> 1;            // N tile == gate index
    const int n_ = lane & 15;
    const int q_ = lane >> 4;

    // ---- one-time: B fragments (weights) resident in VGPRs, fp16 hi/lo ----
    const int jg = nt * 512 + u0 + n_;          // global z-column for this lane
    h8 Bh[18], Bl[18];
    #pragma unroll
    for (int c = 0; c < 18; ++c) {
        #pragma unroll
        for (int e = 0; e < 8; ++e) {
            const int kk = c * 32 + q_ * 8 + e;
            float v;
            if (c < 2) v = W[(size_t)kk * G4H + jg];            // k < 64 always
            else       v = U[(size_t)(kk - I_) * G4H + jg];
            const HiLo hl = cvt_hilo(v);
            Bh[c][e] = hl.hi;
            Bl[c][e] = hl.lo;
        }
    }
    if (tid < 64) bsz[tid] = bias[((tid >> 4) << 9) + u0 + (tid & 15)];

    // ---- gate-update layout: one (row, unit) per thread ----
    const int urow = tid >> 4;
    const int uu   = tid & 15;
    const float tau_r = tau[u0 + uu];
    const float s_r   = sph[u0 + uu];
    float c_st = 0.f;

    // ---- staging geometry ----
    const int xr = tid >> 4, xc4 = (tid & 15) << 2;     // x: 1 float4/thread
    const int hr0 = tid >> 7, hk4 = (tid & 127) << 2;   // h: 8 float4/thread
    float4 xv = *(const float4*)(x + ((size_t)(b0 + xr) * T_ + 0) * I_ + xc4);

    const int rowA = mt * 16 + n_;     // A-frag row (m = lane&15 within M tile)
    const int kof = q_ * 8;            // A-frag k offset within 32-chunk

    int cur = 0;
    for (int t = 0; t < T_; ++t) {
        if (t == 0) {
            h4v xh, xl;
            HiLo c0v = cvt_hilo(xv.x), c1v = cvt_hilo(xv.y),
                 c2v = cvt_hilo(xv.z), c3v = cvt_hilo(xv.w);
            xh[0] = c0v.hi; xl[0] = c0v.lo; xh[1] = c1v.hi; xl[1] = c1v.lo;
            xh[2] = c2v.hi; xl[2] = c2v.lo; xh[3] = c3v.hi; xl[3] = c3v.lo;
            *(h4v*)&Ah[xr][xc4] = xh; *(h4v*)&Al[xr][xc4] = xl;
            h4v z = {(_Float16)0.f, (_Float16)0.f, (_Float16)0.f, (_Float16)0.f};
            #pragma unroll
            for (int it = 0; it < 8; ++it) {
                const int r = hr0 + 4 * it;
                *(h4v*)&Ah[r][I_ + hk4] = z;
                *(h4v*)&Al[r][I_ + hk4] = z;
            }
        } else {
            const float* hb = g_h[cur] + (size_t)(b0 + hr0) * H_ + hk4;
            v4f a0, a1, a2, a3, a4, a5, a6, a7;
            asm volatile(
                "global_load_dwordx4 %0, %8, off sc0 sc1\n\t"
                "global_load_dwordx4 %1, %9, off sc0 sc1\n\t"
                "global_load_dwordx4 %2, %10, off sc0 sc1\n\t"
                "global_load_dwordx4 %3, %11, off sc0 sc1\n\t"
                "global_load_dwordx4 %4, %12, off sc0 sc1\n\t"
                "global_load_dwordx4 %5, %13, off sc0 sc1\n\t"
                "global_load_dwordx4 %6, %14, off sc0 sc1\n\t"
                "global_load_dwordx4 %7, %15, off sc0 sc1"
                : "=&v"(a0), "=&v"(a1), "=&v"(a2), "=&v"(a3),
                  "=&v"(a4), "=&v"(a5), "=&v"(a6), "=&v"(a7)
                : "v"(hb),            "v"(hb + 4 * H_),
                  "v"(hb + 8 * H_),   "v"(hb + 12 * H_),
                  "v"(hb + 16 * H_),  "v"(hb + 20 * H_),
                  "v"(hb + 24 * H_),  "v"(hb + 28 * H_)
                : "memory");
            // overlap: stage x while h loads are in flight (doesn't touch a0..a7)
            h4v xh, xl;
            HiLo c0v = cvt_hilo(xv.x), c1v = cvt_hilo(xv.y),
                 c2v = cvt_hilo(xv.z), c3v = cvt_hilo(xv.w);
            xh[0] = c0v.hi; xl[0] = c0v.lo; xh[1] = c1v.hi; xl[1] = c1v.lo;
            xh[2] = c2v.hi; xl[2] = c2v.lo; xh[3] = c3v.hi; xl[3] = c3v.lo;
            *(h4v*)&Ah[xr][xc4] = xh; *(h4v*)&Al[xr][xc4] = xl;
            // CRITICAL: route a0..a7 THROUGH the waitcnt asm ("+v") so every
            // consumer is data-dependent on the wait. (Round-5 NaN bug: a
            // standalone waitcnt asm let the compiler schedule uses of a0..a7
            // before vmcnt retired.)
            asm volatile("s_waitcnt vmcnt(0)"
                : "+v"(a0), "+v"(a1), "+v"(a2), "+v"(a3),
                  "+v"(a4), "+v"(a5), "+v"(a6), "+v"(a7)
                :: "memory");
            const v4f av[8] = {a0, a1, a2, a3, a4, a5, a6, a7};
            #pragma unroll
            for (int it = 0; it < 8; ++it) {
                const int r = hr0 + 4 * it;
                h4v hh, hlv;
                HiLo e0 = cvt_hilo(av[it][0]), e1 = cvt_hilo(av[it][1]),
                     e2 = cvt_hilo(av[it][2]), e3 = cvt_hilo(av[it][3]);
                hh[0] = e0.hi; hlv[0] = e0.lo; hh[1] = e1.hi; hlv[1] = e1.lo;
                hh[2] = e2.hi; hlv[2] = e2.lo; hh[3] = e3.hi; hlv[3] = e3.lo;
                *(h4v*)&Ah[r][I_ + hk4] = hh;
                *(h4v*)&Al[r][I_ + hk4] = hlv;
            }
        }
        __syncthreads();

        // prefetch next x (in flight through MFMA + barrier)
        {
            const int tn = (t < T_ - 1) ? t + 1 : t;
            xv = *(const float4*)(x + ((size_t)(b0 + xr) * T_ + tn) * I_ + xc4);
        }

        // ---- MFMA: z[16x16] = E_tile @ Wcol_tile, fp16 hi/lo 3-product ----
        f4 ac0 = {0.f, 0.f, 0.f, 0.f};
        f4 ac1 = {0.f, 0.f, 0.f, 0.f};
        f4 ac2 = {0.f, 0.f, 0.f, 0.f};
        #pragma unroll
        for (int c = 0; c < 18; ++c) {
            const h8 ah = *(const h8*)&Ah[rowA][c * 32 + kof];
            const h8 al = *(const h8*)&Al[rowA][c * 32 + kof];
            ac0 = __builtin_amdgcn_mfma_f32_16x16x32_f16(ah, Bh[c], ac0, 0, 0, 0);
            ac1 = __builtin_amdgcn_mfma_f32_16x16x32_f16(ah, Bl[c], ac1, 0, 0, 0);
            ac2 = __builtin_amdgcn_mfma_f32_16x16x32_f16(al, Bh[c], ac2, 0, 0, 0);
        }
        const f4 zt = ac0 + ac1 + ac2;
        {
            const int colz = nt * 16 + n_;
            const int rz = mt * 16 + q_ * 4;   // C-layout: row=(lane>>4)*4+reg
            zs[rz + 0][colz] = zt[0];
            zs[rz + 1][colz] = zt[1];
            zs[rz + 2][colz] = zt[2];
            zs[rz + 3][colz] = zt[3];
        }
        __syncthreads();

        // ---- gates + phased time-gate ----
        {
            const float zi = zs[urow][uu]      + bsz[uu];
            const float zf = zs[urow][16 + uu] + bsz[16 + uu];
            const float zg = zs[urow][32 + uu] + bsz[32 + uu];
            const float zo = zs[urow][48 + uu] + bsz[48 + uu];
            const float si = 1.f / (1.f + __expf(-zi));
            const float sf = 1.f / (1.f + __expf(-zf));
            const float so = 1.f / (1.f + __expf(-zo));
            const float ct = sf * c_st + si * tanhf(zg);
            const float ht = so * tanhf(ct);
            float aa = (float)t - s_r;
            float rr = fmodf(aa, tau_r);
            if (rr < 0.f) rr += tau_r;
            const float phi = rr / tau_r;
            float kk;
            if (phi < 0.5f * R_ON_F)      kk = phi * (2.f / R_ON_F);
            else if (phi < R_ON_F)        kk = 2.f - phi * (2.f / R_ON_F);
            else                          kk = ALPHA_F * phi;
            // hprev reconstructed exactly (hi+lo) from staged operand
            const float hprev = (float)Ah[urow][I_ + u0 + uu] + (float)Al[urow][I_ + u0 + uu];
            const float hn = kk * ht + (1.f - kk) * hprev;
            c_st = kk * ct + (1.f - kk) * c_st;
            float* gp = g_h[cur ^ 1] + (size_t)(b0 + urow) * H_ + (u0 + uu);
            asm volatile("global_store_dword %0, %1, off sc0 sc1"
                         :: "v"(gp), "v"(hn) : "memory");
            asm volatile("s_waitcnt vmcnt(0)" ::: "memory");
        }
        cur ^= 1;
        group_barrier(bt);
    }

    // ---- epilogue: wg b handles batch row b: LN + collapsed dense head ----
    {
        const int b = blockIdx.x;
        float hv;
        const float* hp = g_h[cur] + (size_t)b * H_ + tid;
        asm volatile("global_load_dword %0, %1, off sc0 sc1\n\ts_waitcnt vmcnt(0)"
                     : "=v"(hv) : "v"(hp) : "memory");
        float s1 = hv, s2 = hv * hv;
        #pragma unroll
        for (int off = 32; off > 0; off >>= 1) {
            s1 += __shfl_down(s1, off, 64);
            s2 += __shfl_down(s2, off, 64);
        }
        const int ln = tid & 63;
        if (ln == 0) { red[wv] = s1; red[8 + wv] = s2; }
        __syncthreads();
        float S1 = 0.f, S2 = 0.f;
        #pragma unroll
        for (int w = 0; w < 8; ++w) { S1 += red[w]; S2 += red[8 + w]; }
        const float mu = S1 * (1.f / 512.f);
        const float var = S2 * (1.f / 512.f) - mu * mu;
        const float rstd = rsqrtf(var + LN_EPS_F);
        const float hn = (hv - mu) * rstd * ln_g[tid] + ln_b[tid];
        float w12 = 0.f;
        const float* w1p = W1 + (size_t)tid * 256;
        #pragma unroll 4
        for (int d = 0; d < 256; ++d) w12 = fmaf(w1p[d], W2[d], w12);
        float contrib = hn * w12;
        if (tid < 256) contrib = fmaf(b1[tid], W2[tid], contrib);
        #pragma unroll
        for (int off = 32; off > 0; off >>= 1) contrib += __shfl_down(contrib, off, 64);
        __syncthreads();
        if (ln == 0) red[wv] = contrib;
        __syncthreads();
        if (tid == 0) {
            float tot = b2[0];
            #pragma unroll
            for (int w = 0; w < 8; ++w) tot += red[w];
            out[b] = tot;
        }
    }
}

extern "C" void kernel_launch(void* const* d_in, const int* in_sizes, int n_in,
                              void* d_out, int out_size, void* d_ws, size_t ws_size,
                              hipStream_t stream) {
    const float* x   = (const float*)d_in[0];
    const float* W   = (const float*)d_in[1];
    const float* U   = (const float*)d_in[2];
    const float* b   = (const float*)d_in[3];
    const float* tau = (const float*)d_in[4];
    const float* s   = (const float*)d_in[5];
    const float* lng = (const float*)d_in[6];
    const float* lnb = (const float*)d_in[7];
    const float* W1  = (const float*)d_in[8];
    const float* b1  = (const float*)d_in[9];
    const float* W2  = (const float*)d_in[10];
    const float* b2  = (const float*)d_in[11];
    float* out = (float*)d_out;
    plstm_scan_kernel<<<dim3(NB), dim3(NT), 0, stream>>>(
        x, W, U, b, tau, s, lng, lnb, W1, b1, W2, b2, out);
}